// Round 5
// baseline (350.427 us; speedup 1.0000x reference)
//
#include <hip/hip_runtime.h>

#define NN 100000
#define NE 1600000
#define D 128
#define BN_EPS 1e-5f

#define NB 782        // ceil(NN / 128) buckets, bucket = dst >> 7
#define NWG_BIN 200   // workgroups in hist/scatter passes
#define CHUNK 8000    // NE / NWG_BIN, exact
#define ZOFF (NN*64)  // u32-offset of the zero row in H

typedef __attribute__((ext_vector_type(4))) _Float16 f16x4;
typedef __attribute__((ext_vector_type(4))) float f32x4;

static __device__ __forceinline__ float frelu(float x){ return x > 0.f ? x : 0.f; }

// bf16 helpers (RNE pack, cheap unpack)
static __device__ __forceinline__ unsigned short f2bf(float f){
  unsigned int u = __float_as_uint(f);
  u += 0x7fffu + ((u >> 16) & 1u);
  return (unsigned short)(u >> 16);
}
static __device__ __forceinline__ float bflo(unsigned int p){ return __uint_as_float(p << 16); }
static __device__ __forceinline__ float bfhi(unsigned int p){ return __uint_as_float(p & 0xffff0000u); }

// ---------------- init: zero BN sums + zero sentinel row NN of H ----------------
__global__ void k_init(float* __restrict__ colsum, unsigned int* __restrict__ hw){
  int i = threadIdx.x;
  if (i < 2*D) colsum[i] = 0.f;
  if (i < 64) hw[ZOFF + i] = 0u;   // zero row stays valid for both layers
}

// ---------------- pack W (f32 row-major [k][n]) into f16 MFMA B-fragment order ----
__global__ __launch_bounds__(256) void k_wprep(const float* __restrict__ W1f, const float* __restrict__ W2f,
                                               unsigned long long* __restrict__ P1, unsigned long long* __restrict__ P2){
  const float* W = blockIdx.x ? W2f : W1f;
  unsigned long long* P = blockIdx.x ? P2 : P1;
  int t = threadIdx.x;
  for (int i = 0; i < 16; i++){
    int s = t*16 + i;
    int l = s & 63, kt = (s >> 6) & 7, nt = s >> 9;
    int krow = kt*16 + ((l >> 4) << 2);
    int col = nt*16 + (l & 15);
    f16x4 v;
    #pragma unroll
    for (int j = 0; j < 4; j++) v[j] = (_Float16)W[(krow + j)*D + col];
    P[s] = __builtin_bit_cast(unsigned long long, v);
  }
}

// ---------------- CSR build, pass 1: per-WG bucket histogram (LDS only) ------
__global__ __launch_bounds__(256) void kb_hist(const int* __restrict__ ei, int* __restrict__ wgHist){
  __shared__ int hist[NB];
  int tid = threadIdx.x, w = blockIdx.x;
  for (int i = tid; i < NB; i += 256) hist[i] = 0;
  __syncthreads();
  int base = w*CHUNK;
  for (int e = base + tid; e < base + CHUNK; e += 256)
    atomicAdd(&hist[ei[NE + e] >> 7], 1);
  __syncthreads();
  for (int i = tid; i < NB; i += 256) wgHist[w*NB + i] = hist[i];
}

// ---- pass 2a: for each bucket, exclusive scan across WGs + bucket totals ----
__global__ __launch_bounds__(256) void kb_scan(int* __restrict__ wgHist, int* __restrict__ bucketTotal){
  __shared__ int lds[256];
  int b = blockIdx.x, t = threadIdx.x;
  int v = (t < NWG_BIN) ? wgHist[t*NB + b] : 0;
  lds[t] = v; __syncthreads();
  for (int off = 1; off < 256; off <<= 1){
    int u = (t >= off) ? lds[t - off] : 0;
    __syncthreads(); lds[t] += u; __syncthreads();
  }
  if (t < NWG_BIN) wgHist[t*NB + b] = lds[t] - v;  // exclusive along w
  if (t == 255) bucketTotal[b] = lds[255];
}

// ---- pass 2b: exclusive scan of bucket totals -> bucketStart[0..NB] ---------
__global__ __launch_bounds__(256) void kb_scan2(const int* __restrict__ bucketTotal, int* __restrict__ bucketStart){
  __shared__ int lds[256];
  int t = threadIdx.x;
  int v[4]; int s = 0;
  #pragma unroll
  for (int j = 0; j < 4; j++){ int i = t*4 + j; v[j] = (i < NB) ? bucketTotal[i] : 0; s += v[j]; }
  lds[t] = s; __syncthreads();
  for (int off = 1; off < 256; off <<= 1){
    int u = (t >= off) ? lds[t - off] : 0;
    __syncthreads(); lds[t] += u; __syncthreads();
  }
  int ex = lds[t] - s;
  #pragma unroll
  for (int j = 0; j < 4; j++){ int i = t*4 + j; if (i <= NB) bucketStart[i] = ex; ex += v[j]; }
}

// ---- pass 3: scatter edges into bucket-sorted array; pack (src<<7)|(dst&127) ----
__global__ __launch_bounds__(256) void kb_scatter(const int* __restrict__ ei, const int* __restrict__ wgHist,
                                                  const int* __restrict__ bucketStart, unsigned int* __restrict__ binned){
  __shared__ int fillB[NB];
  __shared__ int baseB[NB];
  int tid = threadIdx.x, w = blockIdx.x;
  for (int i = tid; i < NB; i += 256){ fillB[i] = 0; baseB[i] = bucketStart[i] + wgHist[w*NB + i]; }
  __syncthreads();
  int base = w*CHUNK;
  for (int e = base + tid; e < base + CHUNK; e += 256){
    int s = ei[e], d = ei[NE + e];
    int b = d >> 7;
    int r = atomicAdd(&fillB[b], 1);
    binned[baseB[b] + r] = ((unsigned)s << 7) | (unsigned)(d & 127);
  }
}

// ---- pass 4: per-bucket -> cnt, padded rowStart, dinv, colIdx (src*64, pad=ZOFF) ----
__global__ __launch_bounds__(256) void kb_node(const unsigned int* __restrict__ binned, const int* __restrict__ bucketStart,
                                               int* __restrict__ cnt, int* __restrict__ rowStart,
                                               float* __restrict__ dinv, int* __restrict__ colIdx){
  __shared__ int ncnt[128], roff[128], nfill[128];
  int b = blockIdx.x, t = threadIdx.x;
  int s0 = bucketStart[b], s1 = bucketStart[b + 1];
  int node0 = b << 7;
  int nNodes = min(128, NN - node0);
  if (t < 128){ ncnt[t] = 0; nfill[t] = 0; }
  __syncthreads();
  for (int e = s0 + t; e < s1; e += 256)
    atomicAdd(&ncnt[binned[e] & 127], 1);
  __syncthreads();
  if (t < 128) roff[t] = ncnt[t];
  __syncthreads();
  for (int off = 1; off < 128; off <<= 1){
    int u = (t >= off && t < 128) ? roff[t - off] : 0;
    __syncthreads(); if (t < 128) roff[t] += u; __syncthreads();
  }
  if (t < nNodes){
    int n = ncnt[t];
    int padBase = s0 + (roff[t] - n) + 7*(node0 + t);
    rowStart[node0 + t] = padBase;
    cnt[node0 + t] = n;
    dinv[node0 + t] = rsqrtf((float)(n + 1));
    int nP = (n + 7) & ~7;
    for (int i = n; i < nP; i++) colIdx[padBase + i] = ZOFF;  // zero-row sentinel
  }
  __syncthreads();
  for (int e = s0 + t; e < s1; e += 256){
    unsigned int ed = binned[e];
    int l = ed & 127;
    int r = atomicAdd(&nfill[l], 1);
    colIdx[s0 + (roff[l] - ncnt[l]) + 7*(node0 + l) + r] = (int)((ed >> 7) << 6);  // src*64
  }
}

// ---------------- GEMM layer 1: H[r] = bf16( dinv[r] * (X[r] @ W) ), f32 input ----
__global__ __launch_bounds__(256) void k_gemm1(const float* __restrict__ X,
                                               const unsigned long long* __restrict__ Wpk,
                                               const float* __restrict__ dinv,
                                               unsigned short* __restrict__ H){
  int tid = threadIdx.x, lane = tid & 63;
  int row0 = blockIdx.x*64 + (tid >> 6)*16;
  int arow = row0 + (lane & 15); if (arow >= NN) arow = NN - 1;
  int kg = lane >> 4;  // 0..3

  const float4* X4 = (const float4*)X;
  f16x4 a[8];
  #pragma unroll
  for (int kt = 0; kt < 8; kt++){
    float4 xv = X4[(size_t)arow*32 + kt*4 + kg];
    f16x4 av;
    av[0] = (_Float16)xv.x; av[1] = (_Float16)xv.y;
    av[2] = (_Float16)xv.z; av[3] = (_Float16)xv.w;
    a[kt] = av;
  }

  f32x4 acc[8];
  #pragma unroll
  for (int nt = 0; nt < 8; nt++){ acc[nt][0] = 0.f; acc[nt][1] = 0.f; acc[nt][2] = 0.f; acc[nt][3] = 0.f; }

  #pragma unroll
  for (int kt = 0; kt < 8; kt++){
    #pragma unroll
    for (int nt = 0; nt < 8; nt++){
      f16x4 bfr = __builtin_bit_cast(f16x4, Wpk[(nt*8 + kt)*64 + lane]);
      acc[nt] = __builtin_amdgcn_mfma_f32_16x16x16f16(a[kt], bfr, acc[nt], 0, 0, 0);
    }
  }

  int rbase = row0 + kg*4;
  float4 dv = *(const float4*)&dinv[rbase];
  #pragma unroll
  for (int r = 0; r < 4; r++){
    int row = rbase + r;
    if (row < NN){
      float sc = (r == 0) ? dv.x : (r == 1) ? dv.y : (r == 2) ? dv.z : dv.w;
      #pragma unroll
      for (int nt = 0; nt < 8; nt++)
        H[(size_t)row*D + nt*16 + (lane & 15)] = f2bf(acc[nt][r]*sc);
    }
  }
}

// ---------------- GEMM layer 2: input = relu(gb*aggb + bb) from bf16 agg -------
__global__ __launch_bounds__(256) void k_gemm2(const unsigned int* __restrict__ A,
                                               const float* __restrict__ gb, const float* __restrict__ bb,
                                               const unsigned long long* __restrict__ Wpk,
                                               const float* __restrict__ dinv,
                                               unsigned short* __restrict__ H){
  int tid = threadIdx.x, lane = tid & 63;
  int row0 = blockIdx.x*64 + (tid >> 6)*16;
  int arow = row0 + (lane & 15); if (arow >= NN) arow = NN - 1;
  int kg = lane >> 4;  // 0..3

  const uint2* A2 = (const uint2*)A;
  f16x4 a[8];
  #pragma unroll
  for (int kt = 0; kt < 8; kt++){
    uint2 v = A2[(size_t)arow*32 + kt*4 + kg];
    int c0 = kt*16 + kg*4;
    float4 g = *(const float4*)&gb[c0];
    float4 bo = *(const float4*)&bb[c0];
    f16x4 av;
    av[0] = (_Float16)frelu(bflo(v.x)*g.x + bo.x);
    av[1] = (_Float16)frelu(bfhi(v.x)*g.y + bo.y);
    av[2] = (_Float16)frelu(bflo(v.y)*g.z + bo.z);
    av[3] = (_Float16)frelu(bfhi(v.y)*g.w + bo.w);
    a[kt] = av;
  }

  f32x4 acc[8];
  #pragma unroll
  for (int nt = 0; nt < 8; nt++){ acc[nt][0] = 0.f; acc[nt][1] = 0.f; acc[nt][2] = 0.f; acc[nt][3] = 0.f; }

  #pragma unroll
  for (int kt = 0; kt < 8; kt++){
    #pragma unroll
    for (int nt = 0; nt < 8; nt++){
      f16x4 bfr = __builtin_bit_cast(f16x4, Wpk[(nt*8 + kt)*64 + lane]);
      acc[nt] = __builtin_amdgcn_mfma_f32_16x16x16f16(a[kt], bfr, acc[nt], 0, 0, 0);
    }
  }

  int rbase = row0 + kg*4;
  float4 dv = *(const float4*)&dinv[rbase];
  #pragma unroll
  for (int r = 0; r < 4; r++){
    int row = rbase + r;
    if (row < NN){
      float sc = (r == 0) ? dv.x : (r == 1) ? dv.y : (r == 2) ? dv.z : dv.w;
      #pragma unroll
      for (int nt = 0; nt < 8; nt++)
        H[(size_t)row*D + nt*16 + (lane & 15)] = f2bf(acc[nt][r]*sc);
    }
  }
}

// ---------------- aggregate: wave = 2 nodes x 1 column-half, XCD-sharded halves ----
// block b: node group idx = (b>>3)*4 + (b&3), half = (b>>2)&1  (halves pinned to XCD sets)
__global__ __launch_bounds__(256) void k_agg(const unsigned int* __restrict__ Hp,
                                             const float* __restrict__ dinv,
                                             const int* __restrict__ rowStart,
                                             const int* __restrict__ cnt,
                                             const int* __restrict__ colIdx,
                                             unsigned int* __restrict__ outb){
  int b = blockIdx.x;
  int idx = (b >> 3)*4 + (b & 3);
  int col = ((b >> 2) & 1)*32 + (threadIdx.x & 31);
  int node = idx*8 + ((threadIdx.x >> 6) << 1) + ((threadIdx.x >> 5) & 1);

  float di = dinv[node];
  int beg = rowStart[node];
  int n = cnt[node];
  int nPad = (n + 7) & ~7;
  int nm = max(nPad, __shfl_xor(nPad, 32));

  unsigned int sv = Hp[node*64 + col];   // self (pre-scaled by its dinv)
  float x0 = bflo(sv), y0 = bfhi(sv);
  float x1=0.f,y1=0.f,x2=0.f,y2=0.f,x3=0.f,y3=0.f;
  float x4=0.f,y4=0.f,x5=0.f,y5=0.f,x6=0.f,y6=0.f,x7=0.f,y7=0.f;

  for (int j = 0; j < nm; j += 8){
    bool act = j < nPad;   // shorter node in the wave gathers the zero row
    int i0 = act ? colIdx[beg+j  ] : ZOFF;
    int i1 = act ? colIdx[beg+j+1] : ZOFF;
    int i2 = act ? colIdx[beg+j+2] : ZOFF;
    int i3 = act ? colIdx[beg+j+3] : ZOFF;
    int i4 = act ? colIdx[beg+j+4] : ZOFF;
    int i5 = act ? colIdx[beg+j+5] : ZOFF;
    int i6 = act ? colIdx[beg+j+6] : ZOFF;
    int i7 = act ? colIdx[beg+j+7] : ZOFF;
    unsigned int v0 = Hp[i0 + col];
    unsigned int v1 = Hp[i1 + col];
    unsigned int v2 = Hp[i2 + col];
    unsigned int v3 = Hp[i3 + col];
    unsigned int v4 = Hp[i4 + col];
    unsigned int v5 = Hp[i5 + col];
    unsigned int v6 = Hp[i6 + col];
    unsigned int v7 = Hp[i7 + col];
    x0 += bflo(v0); y0 += bfhi(v0);
    x1 += bflo(v1); y1 += bfhi(v1);
    x2 += bflo(v2); y2 += bfhi(v2);
    x3 += bflo(v3); y3 += bfhi(v3);
    x4 += bflo(v4); y4 += bfhi(v4);
    x5 += bflo(v5); y5 += bfhi(v5);
    x6 += bflo(v6); y6 += bfhi(v6);
    x7 += bflo(v7); y7 += bfhi(v7);
  }

  float sx = ((x0 + x1) + (x2 + x3)) + ((x4 + x5) + (x6 + x7));
  float sy = ((y0 + y1) + (y2 + y3)) + ((y4 + y5) + (y6 + y7));
  unsigned int pk = (unsigned int)f2bf(di*sx) | ((unsigned int)f2bf(di*sy) << 16);
  outb[node*64 + col] = pk;
}

// ---------------- BN column sums over bf16 agg ----------------
__global__ __launch_bounds__(256) void k_bnreduce(const unsigned int* __restrict__ A, float* __restrict__ colsum){
  int tid = threadIdx.x;
  int c2 = tid & 63;   // column pair (2c2, 2c2+1)
  int rg = tid >> 6;   // 0..3
  float slo = 0.f, shi = 0.f, qlo = 0.f, qhi = 0.f;
  for (int r = blockIdx.x*4 + rg; r < NN; r += gridDim.x*4){
    unsigned int v = A[(size_t)r*64 + c2];
    float lo = bflo(v), hi = bfhi(v);
    slo += lo; shi += hi; qlo += lo*lo; qhi += hi*hi;
  }
  __shared__ float2 lds[256];
  lds[tid] = make_float2(slo, qlo); __syncthreads();
  if (rg == 0){
    float2 b = lds[c2 + 64], c = lds[c2 + 128], d = lds[c2 + 192];
    atomicAdd(&colsum[2*c2],     slo + b.x + c.x + d.x);
    atomicAdd(&colsum[D + 2*c2], qlo + b.y + c.y + d.y);
  }
  __syncthreads();
  lds[tid] = make_float2(shi, qhi); __syncthreads();
  if (rg == 0){
    float2 b = lds[c2 + 64], c = lds[c2 + 128], d = lds[c2 + 192];
    atomicAdd(&colsum[2*c2 + 1],     shi + b.x + c.x + d.x);
    atomicAdd(&colsum[D + 2*c2 + 1], qhi + b.y + c.y + d.y);
  }
}

// mu/rstd -> folded gb/bb, then zero partial sums for next layer/call
__global__ void k_bnfinal(float* __restrict__ colsum, const float* __restrict__ gamma,
                          const float* __restrict__ beta, float* __restrict__ gb, float* __restrict__ bb){
  int c = threadIdx.x;
  float mu = colsum[c] * (1.f / NN);
  float var = colsum[D + c] * (1.f / NN) - mu*mu;
  float g = gamma[c] * rsqrtf(var + BN_EPS);
  gb[c] = g;
  bb[c] = beta[c] - mu*g;
  colsum[c] = 0.f; colsum[D + c] = 0.f;
}

// ---------------- BN apply + ReLU: bf16 agg -> f32 out ----------------
__global__ __launch_bounds__(256) void k_bnapply(const unsigned int* __restrict__ A, const float* __restrict__ gb,
                                                 const float* __restrict__ bb, float* __restrict__ out){
  int idx = blockIdx.x*256 + threadIdx.x;
  if (idx >= NN*64) return;
  unsigned int v = A[idx];
  int c2 = idx & 63;
  float2 g = ((const float2*)gb)[c2];
  float2 b = ((const float2*)bb)[c2];
  float lo = frelu(bflo(v)*g.x + b.x);
  float hi = frelu(bfhi(v)*g.y + b.y);
  ((float2*)out)[idx] = make_float2(lo, hi);
}

extern "C" void kernel_launch(void* const* d_in, const int* in_sizes, int n_in,
                              void* d_out, int out_size, void* d_ws, size_t ws_size,
                              hipStream_t stream){
  const float* x   = (const float*)d_in[0];
  const int*   ei  = (const int*)d_in[1];   // [2][NE], row0 = src, row1 = dst
  const float* W1  = (const float*)d_in[2];
  const float* g1  = (const float*)d_in[4];
  const float* be1 = (const float*)d_in[5];
  const float* W2  = (const float*)d_in[6];
  const float* g2  = (const float*)d_in[8];
  const float* be2 = (const float*)d_in[9];
  // b1/b2 cancel exactly inside BatchNorm (agg+b - mean(agg+b)) -> skipped.

  float* out = (float*)d_out;
  float* o1 = out;
  float* o2 = out + (size_t)NN*D;

  char* ws = (char*)d_ws;
  int*   cnt         = (int*)(ws + 0);           // 400000 B
  int*   rowStart    = (int*)(ws + 400384);      // 400000 B (padded starts)
  float* dinv        = (float*)(ws + 800768);    // 400000 B
  float* colsum      = (float*)(ws + 1201152);   // 1024 B
  float* gb          = (float*)(ws + 1202176);   // 512 B
  float* bb          = (float*)(ws + 1202688);   // 512 B
  int*   bucketTotal = (int*)(ws + 1203200);     // 3128 B
  int*   bucketStart = (int*)(ws + 1206400);     // 3132 B
  int*   wgHist      = (int*)(ws + 1209600);     // 625600 B
  unsigned long long* Wpk1 = (unsigned long long*)(ws + 1835264);  // 32768 B
  unsigned long long* Wpk2 = (unsigned long long*)(ws + 1868288);  // 32768 B
  int*   colIdx      = (int*)(ws + 1901312);     // (NE+7*NN+256)*4 = 9201024 B
  unsigned int* binned = (unsigned int*)(ws + 11102336);  // 6.4 MB
  unsigned int* aggb = (unsigned int*)(ws + 17502336);    // 25.6 MB (bf16 agg)
  unsigned short* h  = (unsigned short*)(ws + 43102336);  // 25.6 MB + 256 B zero row
  // total ~68.7 MB of ws

  // ---- prep: W fragment packing + graph counting-sort ----
  k_init    <<<1, 256, 0, stream>>>(colsum, (unsigned int*)h);
  k_wprep   <<<2, 256, 0, stream>>>(W1, W2, Wpk1, Wpk2);
  kb_hist   <<<NWG_BIN, 256, 0, stream>>>(ei, wgHist);
  kb_scan   <<<NB, 256, 0, stream>>>(wgHist, bucketTotal);
  kb_scan2  <<<1, 256, 0, stream>>>(bucketTotal, bucketStart);
  kb_scatter<<<NWG_BIN, 256, 0, stream>>>(ei, wgHist, bucketStart, binned);
  kb_node   <<<NB, 256, 0, stream>>>(binned, bucketStart, cnt, rowStart, dinv, colIdx);

  // ---- layer 1 ----
  k_gemm1   <<<(NN + 63)/64, 256, 0, stream>>>(x, Wpk1, dinv, h);
  k_agg     <<<NN/4, 256, 0, stream>>>((const unsigned int*)h, dinv, rowStart, cnt, colIdx, aggb);
  k_bnreduce<<<512, 256, 0, stream>>>(aggb, colsum);
  k_bnfinal <<<1, 128, 0, stream>>>(colsum, g1, be1, gb, bb);
  k_bnapply <<<(NN*64 + 255)/256, 256, 0, stream>>>(aggb, gb, bb, o1);

  // ---- layer 2 (gemm reads bf16 agg + folded BN inline) ----
  k_gemm2   <<<(NN + 63)/64, 256, 0, stream>>>(aggb, gb, bb, Wpk2, dinv, h);
  k_agg     <<<NN/4, 256, 0, stream>>>((const unsigned int*)h, dinv, rowStart, cnt, colIdx, aggb);
  k_bnreduce<<<512, 256, 0, stream>>>(aggb, colsum);
  k_bnfinal <<<1, 128, 0, stream>>>(colsum, g2, be2, gb, bb);
  k_bnapply <<<(NN*64 + 255)/256, 256, 0, stream>>>(aggb, gb, bb, o2);
}